// Round 8
// baseline (578.914 us; speedup 1.0000x reference)
//
#include <hip/hip_runtime.h>
#include <math.h>

#define N_NODES   10000
#define N_EDGES   320000
#define IN_DIM    128
#define HIDDEN    256
#define NUM_LAYERS 6
#define ALPHA     0.1f
#define LN_EPS    1e-5f

__device__ __forceinline__ float gelu_exact(float x) {
    // jax.nn.gelu(approximate=False): 0.5*x*(1+erf(x/sqrt(2)))
    return 0.5f * x * (1.0f + erff(x * 0.70710678118654752440f));
}

__device__ __forceinline__ float wave_sum64(float v) {
#pragma unroll
    for (int i = 32; i > 0; i >>= 1) v += __shfl_xor(v, i);
    return v;
}

// ---------------- graph preprocessing ----------------

__global__ __launch_bounds__(256) void count_deg_kernel(const int* __restrict__ dst,
                                                        int* __restrict__ cnt) {
    int e = blockIdx.x * 256 + threadIdx.x;
    if (e < N_EDGES) atomicAdd(&cnt[dst[e]], 1);
}

__global__ __launch_bounds__(256) void dinv_kernel(const int* __restrict__ cnt,
                                                   float* __restrict__ dinv) {
    int i = blockIdx.x * 256 + threadIdx.x;
    // +1 for the self loop; deg >= 1 always so the deg>0 guard is moot
    if (i < N_NODES) dinv[i] = rsqrtf((float)(cnt[i] + 1));
}

// single-block exclusive scan over 10000 counts -> CSR row offsets
__global__ __launch_bounds__(256) void scan_kernel(const int* __restrict__ cnt,
                                                   int* __restrict__ offs) {
    __shared__ int sums[256];
    __shared__ int bases[257];
    int t = threadIdx.x;
    const int chunk = (N_NODES + 255) / 256;  // 40
    int b0 = t * chunk;
    int b1 = b0 + chunk; if (b1 > N_NODES) b1 = N_NODES;
    if (b0 > N_NODES) b0 = N_NODES;
    int s = 0;
    for (int i = b0; i < b1; ++i) s += cnt[i];
    sums[t] = s;
    __syncthreads();
    if (t == 0) {
        int r = 0;
        for (int i = 0; i < 256; ++i) { bases[i] = r; r += sums[i]; }
        bases[256] = r;
    }
    __syncthreads();
    int r = bases[t];
    for (int i = b0; i < b1; ++i) { offs[i] = r; r += cnt[i]; }
    if (t == 0) offs[N_NODES] = bases[256];
}

__global__ __launch_bounds__(256) void fill_csr_kernel(const int* __restrict__ src,
                                                       const int* __restrict__ dst,
                                                       const int* __restrict__ offs,
                                                       int* __restrict__ cursor,
                                                       int* __restrict__ csr_src) {
    int e = blockIdx.x * 256 + threadIdx.x;
    if (e < N_EDGES) {
        int d = dst[e], s = src[e];
        int pos = atomicAdd(&cursor[d], 1);
        csr_src[offs[d] + pos] = s;
    }
}

// ---------------- tiled fp32 GEMM: C[M,256] = A[M,K] @ B[K,256] ----------------
// 64x64 tile, BK=16, 4x4 micro-tile per thread, 256 threads.
template<int K>
__global__ __launch_bounds__(256) void gemm_kernel(const float* __restrict__ A,
                                                   const float* __restrict__ B,
                                                   float* __restrict__ C) {
    __shared__ float As[16][68];  // [kk][row], 16B-aligned rows
    __shared__ float Bs[16][68];  // [kk][col]

    int tid = threadIdx.x;
    int tx = tid & 15;
    int ty = tid >> 4;
    int row0 = blockIdx.x * 64;
    int col0 = blockIdx.y * 64;

    float acc[4][4] = {};

    for (int k0 = 0; k0 < K; k0 += 16) {
        {
            int idx = tid * 4;
            int r  = idx >> 4;     // 0..63
            int kk = idx & 15;     // 0,4,8,12
            int row = row0 + r;
            if (row < N_NODES) {
                const float4 a4 = *(const float4*)&A[(size_t)row * K + k0 + kk];
                As[kk + 0][r] = a4.x; As[kk + 1][r] = a4.y;
                As[kk + 2][r] = a4.z; As[kk + 3][r] = a4.w;
            } else {
                As[kk + 0][r] = 0.f; As[kk + 1][r] = 0.f;
                As[kk + 2][r] = 0.f; As[kk + 3][r] = 0.f;
            }
        }
        {
            int idx = tid * 4;
            int rb = idx >> 6;     // 0..15
            int cb = idx & 63;     // multiple of 4
            const float4 b4 = *(const float4*)&B[(size_t)(k0 + rb) * HIDDEN + col0 + cb];
            *(float4*)&Bs[rb][cb] = b4;
        }
        __syncthreads();

        #pragma unroll
        for (int kk = 0; kk < 16; ++kk) {
            const float4 a4 = *(const float4*)&As[kk][ty * 4];
            const float4 b4 = *(const float4*)&Bs[kk][tx * 4];
            acc[0][0] += a4.x * b4.x; acc[0][1] += a4.x * b4.y; acc[0][2] += a4.x * b4.z; acc[0][3] += a4.x * b4.w;
            acc[1][0] += a4.y * b4.x; acc[1][1] += a4.y * b4.y; acc[1][2] += a4.y * b4.z; acc[1][3] += a4.y * b4.w;
            acc[2][0] += a4.z * b4.x; acc[2][1] += a4.z * b4.y; acc[2][2] += a4.z * b4.z; acc[2][3] += a4.z * b4.w;
            acc[3][0] += a4.w * b4.x; acc[3][1] += a4.w * b4.y; acc[3][2] += a4.w * b4.z; acc[3][3] += a4.w * b4.w;
        }
        __syncthreads();
    }

    #pragma unroll
    for (int i = 0; i < 4; ++i) {
        int row = row0 + ty * 4 + i;
        if (row < N_NODES) {
            float4 v = make_float4(acc[i][0], acc[i][1], acc[i][2], acc[i][3]);
            *(float4*)&C[(size_t)row * HIDDEN + col0 + tx * 4] = v;
        }
    }
}

// ---------------- input epilogue: GELU + LN on pre-activation, write h0 and cur ----------------
__global__ __launch_bounds__(256) void ln_in_kernel(const float4* __restrict__ pre,
                                                    const float4* __restrict__ b4,
                                                    const float4* __restrict__ g4,
                                                    const float4* __restrict__ beta4,
                                                    float4* __restrict__ h0,
                                                    float4* __restrict__ cur) {
    int n = blockIdx.x * 4 + (threadIdx.x >> 6);
    int lane = threadIdx.x & 63;
    if (n >= N_NODES) return;

    float4 v = pre[(size_t)n * 64 + lane];
    float4 bb = b4[lane];
    float x0 = gelu_exact(v.x + bb.x);
    float x1 = gelu_exact(v.y + bb.y);
    float x2 = gelu_exact(v.z + bb.z);
    float x3 = gelu_exact(v.w + bb.w);

    float mu = wave_sum64(x0 + x1 + x2 + x3) * (1.0f / 256.0f);
    float d0 = x0 - mu, d1 = x1 - mu, d2 = x2 - mu, d3 = x3 - mu;
    float var = wave_sum64(d0 * d0 + d1 * d1 + d2 * d2 + d3 * d3) * (1.0f / 256.0f);
    float r = rsqrtf(var + LN_EPS);

    float4 gg = g4[lane], be = beta4[lane];
    float4 out = make_float4(d0 * r * gg.x + be.x, d1 * r * gg.y + be.y,
                             d2 * r * gg.z + be.z, d3 * r * gg.w + be.w);
    h0[(size_t)n * 64 + lane]  = out;
    cur[(size_t)n * 64 + lane] = out;
}

// ---------------- gather (column-quarter, XCD-partitioned) ----------------
// Grid = 10000 blocks. Dispatch index i -> quarter q=(i&7)>>1, node-block nb=(i>>3)*2+(i&1).
// Under the i%8 XCD round-robin, quarter q runs only on XCDs {2q,2q+1}, so each XCD's
// working set is 64 columns of m (2.56 MB) + csr_src (1.28 MB) + dinv (40 KB) < 4 MiB L2.
// One wave per node-quarter: lane owns one column. norm recomputed from dinv (saves csr_norm).
// Writes pre[n][col] = selfloop + sum_j norm*m[j][col] + bias[col].
__global__ __launch_bounds__(256) void gather_q_kernel(const float* __restrict__ m,
                                                       const float* __restrict__ dinv,
                                                       const int* __restrict__ offs,
                                                       const int* __restrict__ csr_src,
                                                       const float* __restrict__ bias,
                                                       float* __restrict__ pre) {
    int i  = blockIdx.x;
    int q  = (i & 7) >> 1;
    int nb = (i >> 3) * 2 + (i & 1);
    int n  = nb * 4 + (threadIdx.x >> 6);
    int lane = threadIdx.x & 63;
    int col = q * 64 + lane;

    float dn = dinv[n];
    float acc = m[(size_t)n * HIDDEN + col] * (dn * dn);   // self loop

    int e  = offs[n];
    int e1 = offs[n + 1];
    for (; e + 7 < e1; e += 8) {
        int s0 = csr_src[e + 0], s1 = csr_src[e + 1], s2 = csr_src[e + 2], s3 = csr_src[e + 3];
        int s4 = csr_src[e + 4], s5 = csr_src[e + 5], s6 = csr_src[e + 6], s7 = csr_src[e + 7];
        float v0 = m[(size_t)s0 * HIDDEN + col];
        float v1 = m[(size_t)s1 * HIDDEN + col];
        float v2 = m[(size_t)s2 * HIDDEN + col];
        float v3 = m[(size_t)s3 * HIDDEN + col];
        float v4 = m[(size_t)s4 * HIDDEN + col];
        float v5 = m[(size_t)s5 * HIDDEN + col];
        float v6 = m[(size_t)s6 * HIDDEN + col];
        float v7 = m[(size_t)s7 * HIDDEN + col];
        float w0 = dinv[s0] * dn, w1 = dinv[s1] * dn, w2 = dinv[s2] * dn, w3 = dinv[s3] * dn;
        float w4 = dinv[s4] * dn, w5 = dinv[s5] * dn, w6 = dinv[s6] * dn, w7 = dinv[s7] * dn;
        acc += w0 * v0 + w1 * v1 + w2 * v2 + w3 * v3;
        acc += w4 * v4 + w5 * v5 + w6 * v6 + w7 * v7;
    }
    for (; e < e1; ++e) {
        int s = csr_src[e];
        acc += dinv[s] * dn * m[(size_t)s * HIDDEN + col];
    }

    pre[(size_t)n * HIDDEN + col] = acc + bias[col];
}

// ---------------- GELU + LN + residual (reads pre, updates cur in place) ----------------
// one WAVE per node (4 nodes/block); lane owns 4 columns; LN via wave shuffles.
__global__ __launch_bounds__(256) void ln_res_kernel(const float4* __restrict__ pre4,
                                                     const float4* __restrict__ g4,
                                                     const float4* __restrict__ beta4,
                                                     const float4* __restrict__ h04,
                                                     float4* __restrict__ cur4) {
    int n = blockIdx.x * 4 + (threadIdx.x >> 6);
    int lane = threadIdx.x & 63;
    if (n >= N_NODES) return;

    float4 v = pre4[(size_t)n * 64 + lane];   // bias already included
    float x0 = gelu_exact(v.x);
    float x1 = gelu_exact(v.y);
    float x2 = gelu_exact(v.z);
    float x3 = gelu_exact(v.w);

    float mu = wave_sum64(x0 + x1 + x2 + x3) * (1.0f / 256.0f);
    float d0 = x0 - mu, d1 = x1 - mu, d2 = x2 - mu, d3 = x3 - mu;
    float var = wave_sum64(d0 * d0 + d1 * d1 + d2 * d2 + d3 * d3) * (1.0f / 256.0f);
    float r = rsqrtf(var + LN_EPS);

    float4 gg = g4[lane], be = beta4[lane];
    float h0v = d0 * r * gg.x + be.x;
    float h1v = d1 * r * gg.y + be.y;
    float h2v = d2 * r * gg.z + be.z;
    float h3v = d3 * r * gg.w + be.w;

    size_t idx = (size_t)n * 64 + lane;
    float4 c = cur4[idx];
    float4 h = h04[idx];
    float4 o = make_float4(c.x + (1.0f - ALPHA) * h0v + ALPHA * h.x,
                           c.y + (1.0f - ALPHA) * h1v + ALPHA * h.y,
                           c.z + (1.0f - ALPHA) * h2v + ALPHA * h.z,
                           c.w + (1.0f - ALPHA) * h3v + ALPHA * h.w);
    cur4[idx] = o;
}

// ---------------- launcher ----------------

extern "C" void kernel_launch(void* const* d_in, const int* in_sizes, int n_in,
                              void* d_out, int out_size, void* d_ws, size_t ws_size,
                              hipStream_t stream) {
    const float* x      = (const float*)d_in[0];
    const int*   ei     = (const int*)  d_in[1];   // (2, E): [0]=src, [1]=dst
    const float* W_in   = (const float*)d_in[2];
    const float* b_in   = (const float*)d_in[3];
    const float* g_in   = (const float*)d_in[4];
    const float* bt_in  = (const float*)d_in[5];
    const float* Wl     = (const float*)d_in[6];   // (L, 256, 256)
    const float* bl     = (const float*)d_in[7];
    const float* gl     = (const float*)d_in[8];
    const float* betal  = (const float*)d_in[9];

    const int* src = ei;
    const int* dst = ei + N_EDGES;

    float* cur = (float*)d_out;

    char* w = (char*)d_ws;
    size_t off = 0;
    auto alloc = [&](size_t bytes) -> void* {
        void* p = w + off;
        off = (off + bytes + 255) & ~(size_t)255;
        return p;
    };
    int*   cnt      = (int*)  alloc(N_NODES * sizeof(int));
    int*   cursor   = (int*)  alloc(N_NODES * sizeof(int));
    int*   offs     = (int*)  alloc((N_NODES + 1) * sizeof(int));
    float* dinv     = (float*)alloc(N_NODES * sizeof(float));
    int*   csr_src  = (int*)  alloc(N_EDGES * sizeof(int));
    float* h0       = (float*)alloc((size_t)N_NODES * HIDDEN * sizeof(float));
    float* m        = (float*)alloc((size_t)N_NODES * HIDDEN * sizeof(float));
    float* pre      = (float*)alloc((size_t)N_NODES * HIDDEN * sizeof(float));

    hipMemsetAsync(cnt,    0, N_NODES * sizeof(int), stream);
    hipMemsetAsync(cursor, 0, N_NODES * sizeof(int), stream);

    const int EB = (N_EDGES + 255) / 256;
    const int NB = (N_NODES + 255) / 256;
    const int NODE_BLOCKS = (N_NODES + 3) / 4;   // 2500: 1 wave per node, 4 nodes/block

    count_deg_kernel<<<EB, 256, 0, stream>>>(dst, cnt);
    dinv_kernel<<<NB, 256, 0, stream>>>(cnt, dinv);
    scan_kernel<<<1, 256, 0, stream>>>(cnt, offs);
    fill_csr_kernel<<<EB, 256, 0, stream>>>(src, dst, offs, cursor, csr_src);

    dim3 ggrid((N_NODES + 63) / 64, HIDDEN / 64);

    // input block: GEMM (K=128) -> fused GELU+LN writing h0 and cur
    gemm_kernel<IN_DIM><<<ggrid, 256, 0, stream>>>(x, W_in, m);
    ln_in_kernel<<<NODE_BLOCKS, 256, 0, stream>>>((const float4*)m, (const float4*)b_in,
                                                  (const float4*)g_in, (const float4*)bt_in,
                                                  (float4*)h0, (float4*)cur);

    for (int l = 0; l < NUM_LAYERS; ++l) {
        gemm_kernel<HIDDEN><<<ggrid, 256, 0, stream>>>(cur, Wl + (size_t)l * HIDDEN * HIDDEN, m);
        gather_q_kernel<<<NODE_BLOCKS * 4, 256, 0, stream>>>(m, dinv, offs, csr_src,
                                                             bl + l * HIDDEN, pre);
        ln_res_kernel<<<NODE_BLOCKS, 256, 0, stream>>>((const float4*)pre,
                                                       (const float4*)(gl + l * HIDDEN),
                                                       (const float4*)(betal + l * HIDDEN),
                                                       (const float4*)h0, (float4*)cur);
    }
}

// Round 9
// 525.625 us; speedup vs baseline: 1.1014x; 1.1014x over previous
//
#include <hip/hip_runtime.h>
#include <math.h>

#define N_NODES   10000
#define N_EDGES   320000
#define IN_DIM    128
#define HIDDEN    256
#define NUM_LAYERS 6
#define ALPHA     0.1f
#define LN_EPS    1e-5f

__device__ __forceinline__ float gelu_exact(float x) {
    // jax.nn.gelu(approximate=False): 0.5*x*(1+erf(x/sqrt(2)))
    return 0.5f * x * (1.0f + erff(x * 0.70710678118654752440f));
}

__device__ __forceinline__ float wave_sum64(float v) {
#pragma unroll
    for (int i = 32; i > 0; i >>= 1) v += __shfl_xor(v, i);
    return v;
}

// ---------------- graph preprocessing ----------------

__global__ __launch_bounds__(256) void count_deg_kernel(const int* __restrict__ dst,
                                                        int* __restrict__ cnt) {
    int e = blockIdx.x * 256 + threadIdx.x;
    if (e < N_EDGES) atomicAdd(&cnt[dst[e]], 1);
}

__global__ __launch_bounds__(256) void dinv_kernel(const int* __restrict__ cnt,
                                                   float* __restrict__ dinv) {
    int i = blockIdx.x * 256 + threadIdx.x;
    // +1 for the self loop; deg >= 1 always so the deg>0 guard is moot
    if (i < N_NODES) dinv[i] = rsqrtf((float)(cnt[i] + 1));
}

// single-block exclusive scan over 10000 counts -> CSR row offsets
__global__ __launch_bounds__(256) void scan_kernel(const int* __restrict__ cnt,
                                                   int* __restrict__ offs) {
    __shared__ int sums[256];
    __shared__ int bases[257];
    int t = threadIdx.x;
    const int chunk = (N_NODES + 255) / 256;  // 40
    int b0 = t * chunk;
    int b1 = b0 + chunk; if (b1 > N_NODES) b1 = N_NODES;
    if (b0 > N_NODES) b0 = N_NODES;
    int s = 0;
    for (int i = b0; i < b1; ++i) s += cnt[i];
    sums[t] = s;
    __syncthreads();
    if (t == 0) {
        int r = 0;
        for (int i = 0; i < 256; ++i) { bases[i] = r; r += sums[i]; }
        bases[256] = r;
    }
    __syncthreads();
    int r = bases[t];
    for (int i = b0; i < b1; ++i) { offs[i] = r; r += cnt[i]; }
    if (t == 0) offs[N_NODES] = bases[256];
}

__global__ __launch_bounds__(256) void fill_csr_kernel(const int* __restrict__ src,
                                                       const int* __restrict__ dst,
                                                       const int* __restrict__ offs,
                                                       int* __restrict__ cursor,
                                                       int* __restrict__ csr_src) {
    int e = blockIdx.x * 256 + threadIdx.x;
    if (e < N_EDGES) {
        int d = dst[e], s = src[e];
        int pos = atomicAdd(&cursor[d], 1);
        csr_src[offs[d] + pos] = s;
    }
}

// ---------------- tiled fp32 GEMM: C[M,256] = A[M,K] @ B[K,256] ----------------
// 64x64 tile, BK=16, 4x4 micro-tile per thread, 256 threads.
template<int K>
__global__ __launch_bounds__(256) void gemm_kernel(const float* __restrict__ A,
                                                   const float* __restrict__ B,
                                                   float* __restrict__ C) {
    __shared__ float As[16][68];  // [kk][row], 16B-aligned rows
    __shared__ float Bs[16][68];  // [kk][col]

    int tid = threadIdx.x;
    int tx = tid & 15;
    int ty = tid >> 4;
    int row0 = blockIdx.x * 64;
    int col0 = blockIdx.y * 64;

    float acc[4][4] = {};

    for (int k0 = 0; k0 < K; k0 += 16) {
        {
            int idx = tid * 4;
            int r  = idx >> 4;     // 0..63
            int kk = idx & 15;     // 0,4,8,12
            int row = row0 + r;
            if (row < N_NODES) {
                const float4 a4 = *(const float4*)&A[(size_t)row * K + k0 + kk];
                As[kk + 0][r] = a4.x; As[kk + 1][r] = a4.y;
                As[kk + 2][r] = a4.z; As[kk + 3][r] = a4.w;
            } else {
                As[kk + 0][r] = 0.f; As[kk + 1][r] = 0.f;
                As[kk + 2][r] = 0.f; As[kk + 3][r] = 0.f;
            }
        }
        {
            int idx = tid * 4;
            int rb = idx >> 6;     // 0..15
            int cb = idx & 63;     // multiple of 4
            const float4 b4 = *(const float4*)&B[(size_t)(k0 + rb) * HIDDEN + col0 + cb];
            *(float4*)&Bs[rb][cb] = b4;
        }
        __syncthreads();

        #pragma unroll
        for (int kk = 0; kk < 16; ++kk) {
            const float4 a4 = *(const float4*)&As[kk][ty * 4];
            const float4 b4 = *(const float4*)&Bs[kk][tx * 4];
            acc[0][0] += a4.x * b4.x; acc[0][1] += a4.x * b4.y; acc[0][2] += a4.x * b4.z; acc[0][3] += a4.x * b4.w;
            acc[1][0] += a4.y * b4.x; acc[1][1] += a4.y * b4.y; acc[1][2] += a4.y * b4.z; acc[1][3] += a4.y * b4.w;
            acc[2][0] += a4.z * b4.x; acc[2][1] += a4.z * b4.y; acc[2][2] += a4.z * b4.z; acc[2][3] += a4.z * b4.w;
            acc[3][0] += a4.w * b4.x; acc[3][1] += a4.w * b4.y; acc[3][2] += a4.w * b4.z; acc[3][3] += a4.w * b4.w;
        }
        __syncthreads();
    }

    #pragma unroll
    for (int i = 0; i < 4; ++i) {
        int row = row0 + ty * 4 + i;
        if (row < N_NODES) {
            float4 v = make_float4(acc[i][0], acc[i][1], acc[i][2], acc[i][3]);
            *(float4*)&C[(size_t)row * HIDDEN + col0 + tx * 4] = v;
        }
    }
}

// ---------------- input epilogue: GELU + LN on pre-activation, write h0 and cur ----------------
__global__ __launch_bounds__(256) void ln_in_kernel(const float4* __restrict__ pre,
                                                    const float4* __restrict__ b4,
                                                    const float4* __restrict__ g4,
                                                    const float4* __restrict__ beta4,
                                                    float4* __restrict__ h0,
                                                    float4* __restrict__ cur) {
    int n = blockIdx.x * 4 + (threadIdx.x >> 6);
    int lane = threadIdx.x & 63;
    if (n >= N_NODES) return;

    float4 v = pre[(size_t)n * 64 + lane];
    float4 bb = b4[lane];
    float x0 = gelu_exact(v.x + bb.x);
    float x1 = gelu_exact(v.y + bb.y);
    float x2 = gelu_exact(v.z + bb.z);
    float x3 = gelu_exact(v.w + bb.w);

    float mu = wave_sum64(x0 + x1 + x2 + x3) * (1.0f / 256.0f);
    float d0 = x0 - mu, d1 = x1 - mu, d2 = x2 - mu, d3 = x3 - mu;
    float var = wave_sum64(d0 * d0 + d1 * d1 + d2 * d2 + d3 * d3) * (1.0f / 256.0f);
    float r = rsqrtf(var + LN_EPS);

    float4 gg = g4[lane], be = beta4[lane];
    float4 out = make_float4(d0 * r * gg.x + be.x, d1 * r * gg.y + be.y,
                             d2 * r * gg.z + be.z, d3 * r * gg.w + be.w);
    h0[(size_t)n * 64 + lane]  = out;
    cur[(size_t)n * 64 + lane] = out;
}

// ---------------- gather (column-quarter, XCD-partitioned, 4-edge-groups) ----------------
// Grid = 10000 blocks, 4 waves/block. Dispatch index i -> quarter q=(i&7)>>1,
// node-block nb=(i>>3)*2+(i&1); under the i%8 XCD round-robin, quarter q runs on
// XCDs {2q,2q+1} so each XCD's working set (64 cols of m = 2.56 MB + csr 1.28 MB
// + dinv 40 KB) is L2-resident (VERIFIED round 8: FETCH 121->13.4 MB).
// Wave layout: 4 edge-groups x 16 lanes. Each group gathers ONE edge's 64-col
// quarter slice as float4 (16x16B = 256 B; 4 groups = 1 KB per issue slot), x2
// unroll = 8 edges in flight. Cross-group combine = 2 shfl_xor at the end.
__global__ __launch_bounds__(256) void gather_q_kernel(const float4* __restrict__ m4,
                                                       const float* __restrict__ dinv,
                                                       const int* __restrict__ offs,
                                                       const int* __restrict__ csr_src,
                                                       const float4* __restrict__ bias4,
                                                       float4* __restrict__ pre4) {
    int i  = blockIdx.x;
    int q  = (i & 7) >> 1;
    int nb = (i >> 3) * 2 + (i & 1);
    int n  = nb * 4 + (threadIdx.x >> 6);
    int lane = threadIdx.x & 63;
    int g = lane >> 4;                 // edge-group 0..3
    int t = lane & 15;                 // float4 slot within the 64-col quarter
    int cbase = q * 16 + t;            // float4 index within the 64-float4 row

    float dn = dinv[n];

    float4 acc = make_float4(0.f, 0.f, 0.f, 0.f);
    if (g == 0) {                      // self loop, norm = 1/deg
        float4 sv = m4[(size_t)n * 64 + cbase];
        float dn2 = dn * dn;
        acc.x = sv.x * dn2; acc.y = sv.y * dn2; acc.z = sv.z * dn2; acc.w = sv.w * dn2;
    }

    int e1 = offs[n + 1];
    int ee = offs[n] + g;
    for (; ee + 4 < e1; ee += 8) {     // 2 edges per group per iteration
        int sA = csr_src[ee];
        int sB = csr_src[ee + 4];
        float4 vA = m4[(size_t)sA * 64 + cbase];
        float4 vB = m4[(size_t)sB * 64 + cbase];
        float wA = dinv[sA] * dn;
        float wB = dinv[sB] * dn;
        acc.x += wA * vA.x + wB * vB.x;
        acc.y += wA * vA.y + wB * vB.y;
        acc.z += wA * vA.z + wB * vB.z;
        acc.w += wA * vA.w + wB * vB.w;
    }
    if (ee < e1) {
        int s = csr_src[ee];
        float4 v = m4[(size_t)s * 64 + cbase];
        float w = dinv[s] * dn;
        acc.x += w * v.x; acc.y += w * v.y; acc.z += w * v.z; acc.w += w * v.w;
    }

    // combine the 4 edge-groups (lanes that share t)
    #pragma unroll
    for (int off = 16; off <= 32; off <<= 1) {
        acc.x += __shfl_xor(acc.x, off);
        acc.y += __shfl_xor(acc.y, off);
        acc.z += __shfl_xor(acc.z, off);
        acc.w += __shfl_xor(acc.w, off);
    }

    if (g == 0) {
        float4 bb = bias4[cbase];
        pre4[(size_t)n * 64 + cbase] = make_float4(acc.x + bb.x, acc.y + bb.y,
                                                   acc.z + bb.z, acc.w + bb.w);
    }
}

// ---------------- GELU + LN + residual (reads pre, updates cur in place) ----------------
// one WAVE per node (4 nodes/block); lane owns 4 columns; LN via wave shuffles.
__global__ __launch_bounds__(256) void ln_res_kernel(const float4* __restrict__ pre4,
                                                     const float4* __restrict__ g4,
                                                     const float4* __restrict__ beta4,
                                                     const float4* __restrict__ h04,
                                                     float4* __restrict__ cur4) {
    int n = blockIdx.x * 4 + (threadIdx.x >> 6);
    int lane = threadIdx.x & 63;
    if (n >= N_NODES) return;

    float4 v = pre4[(size_t)n * 64 + lane];   // bias already included
    float x0 = gelu_exact(v.x);
    float x1 = gelu_exact(v.y);
    float x2 = gelu_exact(v.z);
    float x3 = gelu_exact(v.w);

    float mu = wave_sum64(x0 + x1 + x2 + x3) * (1.0f / 256.0f);
    float d0 = x0 - mu, d1 = x1 - mu, d2 = x2 - mu, d3 = x3 - mu;
    float var = wave_sum64(d0 * d0 + d1 * d1 + d2 * d2 + d3 * d3) * (1.0f / 256.0f);
    float r = rsqrtf(var + LN_EPS);

    float4 gg = g4[lane], be = beta4[lane];
    float h0v = d0 * r * gg.x + be.x;
    float h1v = d1 * r * gg.y + be.y;
    float h2v = d2 * r * gg.z + be.z;
    float h3v = d3 * r * gg.w + be.w;

    size_t idx = (size_t)n * 64 + lane;
    float4 c = cur4[idx];
    float4 h = h04[idx];
    float4 o = make_float4(c.x + (1.0f - ALPHA) * h0v + ALPHA * h.x,
                           c.y + (1.0f - ALPHA) * h1v + ALPHA * h.y,
                           c.z + (1.0f - ALPHA) * h2v + ALPHA * h.z,
                           c.w + (1.0f - ALPHA) * h3v + ALPHA * h.w);
    cur4[idx] = o;
}

// ---------------- launcher ----------------

extern "C" void kernel_launch(void* const* d_in, const int* in_sizes, int n_in,
                              void* d_out, int out_size, void* d_ws, size_t ws_size,
                              hipStream_t stream) {
    const float* x      = (const float*)d_in[0];
    const int*   ei     = (const int*)  d_in[1];   // (2, E): [0]=src, [1]=dst
    const float* W_in   = (const float*)d_in[2];
    const float* b_in   = (const float*)d_in[3];
    const float* g_in   = (const float*)d_in[4];
    const float* bt_in  = (const float*)d_in[5];
    const float* Wl     = (const float*)d_in[6];   // (L, 256, 256)
    const float* bl     = (const float*)d_in[7];
    const float* gl     = (const float*)d_in[8];
    const float* betal  = (const float*)d_in[9];

    const int* src = ei;
    const int* dst = ei + N_EDGES;

    float* cur = (float*)d_out;

    char* w = (char*)d_ws;
    size_t off = 0;
    auto alloc = [&](size_t bytes) -> void* {
        void* p = w + off;
        off = (off + bytes + 255) & ~(size_t)255;
        return p;
    };
    int*   cnt      = (int*)  alloc(N_NODES * sizeof(int));
    int*   cursor   = (int*)  alloc(N_NODES * sizeof(int));
    int*   offs     = (int*)  alloc((N_NODES + 1) * sizeof(int));
    float* dinv     = (float*)alloc(N_NODES * sizeof(float));
    int*   csr_src  = (int*)  alloc(N_EDGES * sizeof(int));
    float* h0       = (float*)alloc((size_t)N_NODES * HIDDEN * sizeof(float));
    float* m        = (float*)alloc((size_t)N_NODES * HIDDEN * sizeof(float));
    float* pre      = (float*)alloc((size_t)N_NODES * HIDDEN * sizeof(float));

    hipMemsetAsync(cnt,    0, N_NODES * sizeof(int), stream);
    hipMemsetAsync(cursor, 0, N_NODES * sizeof(int), stream);

    const int EB = (N_EDGES + 255) / 256;
    const int NB = (N_NODES + 255) / 256;
    const int NODE_BLOCKS = (N_NODES + 3) / 4;   // 2500: 1 wave per node, 4 nodes/block

    count_deg_kernel<<<EB, 256, 0, stream>>>(dst, cnt);
    dinv_kernel<<<NB, 256, 0, stream>>>(cnt, dinv);
    scan_kernel<<<1, 256, 0, stream>>>(cnt, offs);
    fill_csr_kernel<<<EB, 256, 0, stream>>>(src, dst, offs, cursor, csr_src);

    dim3 ggrid((N_NODES + 63) / 64, HIDDEN / 64);

    // input block: GEMM (K=128) -> fused GELU+LN writing h0 and cur
    gemm_kernel<IN_DIM><<<ggrid, 256, 0, stream>>>(x, W_in, m);
    ln_in_kernel<<<NODE_BLOCKS, 256, 0, stream>>>((const float4*)m, (const float4*)b_in,
                                                  (const float4*)g_in, (const float4*)bt_in,
                                                  (float4*)h0, (float4*)cur);

    for (int l = 0; l < NUM_LAYERS; ++l) {
        gemm_kernel<HIDDEN><<<ggrid, 256, 0, stream>>>(cur, Wl + (size_t)l * HIDDEN * HIDDEN, m);
        gather_q_kernel<<<NODE_BLOCKS * 4, 256, 0, stream>>>((const float4*)m, dinv, offs, csr_src,
                                                             (const float4*)(bl + l * HIDDEN),
                                                             (float4*)pre);
        ln_res_kernel<<<NODE_BLOCKS, 256, 0, stream>>>((const float4*)pre,
                                                       (const float4*)(gl + l * HIDDEN),
                                                       (const float4*)(betal + l * HIDDEN),
                                                       (const float4*)h0, (float4*)cur);
    }
}